// Round 6
// baseline (594.401 us; speedup 1.0000x reference)
//
#include <hip/hip_runtime.h>

typedef __attribute__((ext_vector_type(8))) short short8;
typedef __attribute__((ext_vector_type(4))) float float4v;

#define NNODES 8192
#define SEQLEN 256

static __device__ __forceinline__ float bf2f(unsigned short u) {
  union { unsigned u; float f; } v; v.u = ((unsigned)u) << 16; return v.f;
}
static __device__ __forceinline__ unsigned short f2bf(float f) {
  union { float f; unsigned u; } v; v.f = f;
  unsigned r = v.u + 0x7FFFu + ((v.u >> 16) & 1u);
  return (unsigned short)(r >> 16);
}
// z' is in log2 units (pre-scaled by log2 e)
static __device__ __forceinline__ float sigmL(float zp) {
  float e = __builtin_amdgcn_exp2f(-zp);
  return __builtin_amdgcn_rcpf(1.f + e);
}
static __device__ __forceinline__ float tanhL(float zp) {   // tanh from log2-scaled input
  float e = __builtin_amdgcn_exp2f(zp + zp);
  return (e - 1.f) * __builtin_amdgcn_rcpf(e + 1.f);
}
static __device__ __forceinline__ float tanhR(float x) {    // tanh, real units (for c)
  float e = __builtin_amdgcn_exp2f(2.88539008178f * fminf(x, 20.f));
  return (e - 1.f) * __builtin_amdgcn_rcpf(e + 1.f);
}
static __device__ __forceinline__ void split8(const float* v, short8& hi, short8& lo) {
#pragma unroll
  for (int j = 0; j < 8; ++j) {
    unsigned short h = f2bf(v[j]);
    hi[j] = (short)h;
    lo[j] = (short)f2bf(v[j] - bf2f(h));
  }
}

// v6: ILP-2 — each wave processes 2 independent 16-node tiles (32 nodes/block,
// 256 blocks). Gate weights pre-scaled by log2e; biases folded into MFMA C-init;
// LN factors exchanged through a tiny LDS array (benign redundant writes).
__global__ __launch_bounds__(512, 2)
void lstm_fused(const float* __restrict__ x,
                const float* __restrict__ Wih1, const float* __restrict__ Whh1,
                const float* __restrict__ bih1, const float* __restrict__ bhh1,
                const float* __restrict__ ln_g, const float* __restrict__ ln_b,
                const float* __restrict__ Wih2, const float* __restrict__ Whh2,
                const float* __restrict__ bih2, const float* __restrict__ bhh2,
                float* __restrict__ h2out)
{
  const int tid = threadIdx.x;
  const int w = tid >> 6;
  const int lane = tid & 63;
  const int c = lane & 15;
  const int q = lane >> 4;
  const int cn = lane >> 2;         // cell node 0..15
  const int ch = lane & 3;
  const int hid = w * 4 + ch;
  const int nodeBase = blockIdx.x * 32;
  const float L = 1.44269504089f;

  __shared__ float xlds[2][16 * 257];
  __shared__ __align__(16) float zbuf[2][16 * 132];
  __shared__ __align__(16) unsigned short h1p[2][16 * 40];
  __shared__ __align__(16) unsigned short h2p[2][16 * 40];
  __shared__ __align__(16) float mu2[2][32];

  for (int i = tid; i < 32 * 256; i += 512) {
    int nn = i >> 8, tt = i & 255;
    xlds[nn >> 4][(nn & 15) * 257 + tt] = x[(size_t)(nodeBase + nn) * SEQLEN + tt];
  }

  // ---- B fragments (col c -> brow), hi+lo split, scaled by L ----
  const int brow = (c & 3) * 32 + w * 4 + (c >> 2);
  short8 Bh1h, Bh1l, Bi2h, Bi2l, Bh2h, Bh2l;
  float Gpre, b1pre, b2pre;
  {
    float v[8];
#pragma unroll
    for (int j = 0; j < 8; ++j) v[j] = L * Whh1[brow * 32 + q * 8 + j];
    split8(v, Bh1h, Bh1l);
#pragma unroll
    for (int j = 0; j < 8; ++j) v[j] = L * Wih2[brow * 32 + q * 8 + j] * ln_g[q * 8 + j];
    split8(v, Bi2h, Bi2l);
#pragma unroll
    for (int j = 0; j < 8; ++j) v[j] = L * Whh2[brow * 32 + q * 8 + j];
    split8(v, Bh2h, Bh2l);
    float sG = 0.f, sB = 0.f;
    for (int k = 0; k < 32; ++k) {
      sG += Wih2[brow * 32 + k] * ln_g[k];
      sB += Wih2[brow * 32 + k] * ln_b[k];
    }
    Gpre = L * sG;
    b1pre = L * (bih1[brow] + bhh1[brow]);
    b2pre = L * (sB + bih2[brow] + bhh2[brow]);
  }
  const float4v C1 = {b1pre, b1pre, b1pre, b1pre};
  const float4v C2 = {b2pre, b2pre, b2pre, b2pre};
  const float4v z4 = {0.f, 0.f, 0.f, 0.f};
  // consumer-side x weights (gate rows g*32+hid), scaled by L
  float w1v[4];
#pragma unroll
  for (int g = 0; g < 4; ++g) w1v[g] = L * Wih1[g * 32 + hid];

  // loop-invariant LDS addresses
  int zW[4];
#pragma unroll
  for (int r = 0; r < 4; ++r) zW[r] = (q * 4 + r) * 132 + w * 16 + c;
  const int zR = cn * 132 + hid * 4;
  const int hWr = cn * 40 + hid;
  const int hRd = c * 40 + q * 8;

  short8 h1A[2], h2A[2];
  float c1[2] = {0.f, 0.f}, c2[2] = {0.f, 0.f}, hv2[2];
#pragma unroll
  for (int tl = 0; tl < 2; ++tl) {
    h1A[tl] = short8{0,0,0,0,0,0,0,0};
    h2A[tl] = short8{0,0,0,0,0,0,0,0};
  }
  __syncthreads();

  for (int t = 0; t < SEQLEN; ++t) {
    // ---- layer1 matmuls (both tiles, independent chains) ----
#pragma unroll
    for (int tl = 0; tl < 2; ++tl) {
      float4v za = __builtin_amdgcn_mfma_f32_16x16x32_bf16(h1A[tl], Bh1l, C1, 0, 0, 0);
      za = __builtin_amdgcn_mfma_f32_16x16x32_bf16(h1A[tl], Bh1h, za, 0, 0, 0);
#pragma unroll
      for (int r = 0; r < 4; ++r) zbuf[tl][zW[r]] = za[r];
    }
    // ---- layer1 cells ----
#pragma unroll
    for (int tl = 0; tl < 2; ++tl) {
      float4v zv = *(const float4v*)&zbuf[tl][zR];
      float xv = xlds[tl][cn * 257 + t];
      float zi = fmaf(xv, w1v[0], zv[0]);
      float zf = fmaf(xv, w1v[1], zv[1]);
      float zg = fmaf(xv, w1v[2], zv[2]);
      float zo = fmaf(xv, w1v[3], zv[3]);
      c1[tl] = sigmL(zf) * c1[tl] + sigmL(zi) * tanhL(zg);
      float hv = sigmL(zo) * tanhR(c1[tl]);
      h1p[tl][hWr] = f2bf(hv);
    }
    __syncthreads();                           // B1
#pragma unroll
    for (int tl = 0; tl < 2; ++tl) {
      h1A[tl] = *(const short8*)&h1p[tl][hRd];
      // LN stats for node c (redundant per wave)
      float s = 0.f, s2 = 0.f;
#pragma unroll
      for (int j = 0; j < 8; ++j) {
        float hf = bf2f((unsigned short)h1A[tl][j]);
        s += hf; s2 = fmaf(hf, hf, s2);
      }
      s  += __shfl_xor(s, 16, 64);  s  += __shfl_xor(s, 32, 64);
      s2 += __shfl_xor(s2, 16, 64); s2 += __shfl_xor(s2, 32, 64);
      float mu = s * (1.f / 32.f);
      float var = s2 * (1.f / 32.f) - mu * mu;
      float rstd = rsqrtf(var + 1e-5f);
      if (q < 2) mu2[tl][c * 2 + q] = (q == 0) ? rstd : rstd * mu;
    }
    // ---- layer2 matmuls + folded-LN combine ----
#pragma unroll
    for (int tl = 0; tl < 2; ++tl) {
      float4v da = __builtin_amdgcn_mfma_f32_16x16x32_bf16(h1A[tl], Bi2l, z4, 0, 0, 0);
      da = __builtin_amdgcn_mfma_f32_16x16x32_bf16(h1A[tl], Bi2h, da, 0, 0, 0);
      float4v db = __builtin_amdgcn_mfma_f32_16x16x32_bf16(h2A[tl], Bh2l, C2, 0, 0, 0);
      db = __builtin_amdgcn_mfma_f32_16x16x32_bf16(h2A[tl], Bh2h, db, 0, 0, 0);
#pragma unroll
      for (int r = 0; r < 4; ++r) {
        float2 ab = *(const float2*)&mu2[tl][(q * 4 + r) * 2];  // own-wave write, lgkm-ordered
        zbuf[tl][zW[r]] = fmaf(ab.x, da[r], fmaf(-ab.y, Gpre, db[r]));
      }
    }
    // ---- layer2 cells ----
#pragma unroll
    for (int tl = 0; tl < 2; ++tl) {
      float4v zv = *(const float4v*)&zbuf[tl][zR];
      c2[tl] = sigmL(zv[1]) * c2[tl] + sigmL(zv[0]) * tanhL(zv[2]);
      hv2[tl] = sigmL(zv[3]) * tanhR(c2[tl]);
      h2p[tl][hWr] = f2bf(hv2[tl]);
    }
    __syncthreads();                           // B2
#pragma unroll
    for (int tl = 0; tl < 2; ++tl)
      h2A[tl] = *(const short8*)&h2p[tl][hRd];
  }
#pragma unroll
  for (int tl = 0; tl < 2; ++tl)
    h2out[(size_t)(nodeBase + tl * 16 + cn) * 32 + hid] = hv2[tl];
}

// ---------------- GCN (all f32) ----------------
__global__ void deg_init(float* __restrict__ deg) {
  int i = blockIdx.x * 256 + threadIdx.x;
  if (i < NNODES) deg[i] = 1.f;
}
__global__ void deg_acc(const int* __restrict__ ei, const float* __restrict__ ew,
                        float* __restrict__ deg, int E) {
  int e = blockIdx.x * 256 + threadIdx.x;
  if (e < E) atomicAdd(&deg[ei[E + e]], ew[e]);
}
__global__ void gcn_mm1(const float* __restrict__ h2, const float* __restrict__ Wg1,
                        const float* __restrict__ deg, float* __restrict__ dinv,
                        float* __restrict__ hW, float* __restrict__ agg) {
  __shared__ float wg[32 * 33];
  int tid = threadIdx.x;
  for (int i = tid; i < 1024; i += 256) wg[(i >> 5) * 33 + (i & 31)] = Wg1[i];
  __syncthreads();
  int nl = tid >> 5, j = tid & 31;
  int node = blockIdx.x * 8 + nl;
  const float* hr = h2 + (size_t)node * 32;
  float acc = 0.f;
#pragma unroll
  for (int k = 0; k < 32; ++k) acc = fmaf(hr[k], wg[k * 33 + j], acc);
  float dv = rsqrtf(deg[node]);
  if (j == 0) dinv[node] = dv;
  hW[(size_t)node * 32 + j] = acc;
  agg[(size_t)node * 32 + j] = acc * dv * dv;
}
__global__ void gcn_edge(const int* __restrict__ ei, const float* __restrict__ ew,
                         const float* __restrict__ dinv, const float* __restrict__ hW,
                         float* __restrict__ agg, int E) {
  int gid = blockIdx.x * 256 + threadIdx.x;
  int e = gid >> 5, j = gid & 31;
  if (e >= E) return;
  int s = ei[e], d = ei[E + e];
  float coeff = dinv[s] * ew[e] * dinv[d];
  atomicAdd(&agg[(size_t)d * 32 + j], coeff * hW[(size_t)s * 32 + j]);
}
__global__ void gcn_mid(const float* __restrict__ bg1, const float* __restrict__ Wg2,
                        const float* __restrict__ dinv,
                        float* __restrict__ hW, float* __restrict__ agg) {
  __shared__ float wg[32 * 33];
  __shared__ float g1buf[8][33];
  int tid = threadIdx.x;
  for (int i = tid; i < 1024; i += 256) wg[(i >> 5) * 33 + (i & 31)] = Wg2[i];
  int nl = tid >> 5, j = tid & 31;
  int node = blockIdx.x * 8 + nl;
  float v = agg[(size_t)node * 32 + j] + bg1[j];
  g1buf[nl][j] = (v > 0.f) ? v : expm1f(v);
  __syncthreads();
  float acc = 0.f;
#pragma unroll
  for (int k = 0; k < 32; ++k) acc = fmaf(g1buf[nl][k], wg[k * 33 + j], acc);
  float dv = dinv[node];
  hW[(size_t)node * 32 + j] = acc;
  agg[(size_t)node * 32 + j] = acc * dv * dv;
}
__global__ void final_k(const float* __restrict__ h2, const float* __restrict__ agg,
                        const float* __restrict__ bg2, const float* __restrict__ Wfc,
                        const float* __restrict__ bfc, float* __restrict__ out) {
  int node = blockIdx.x * 256 + threadIdx.x;
  if (node >= NNODES) return;
  const float* ar = agg + (size_t)node * 32;
  float msum = 0.f;
#pragma unroll
  for (int k = 0; k < 32; ++k) {
    float v = ar[k] + bg2[k];
    msum += (v > 0.f) ? v : expm1f(v);
  }
  float mean = msum * (1.f / 32.f);
  const float* hr = h2 + (size_t)node * 32;
  float o0 = bfc[0], o1 = bfc[1];
#pragma unroll
  for (int k = 0; k < 32; ++k) {
    float hv = hr[k];
    o0 = fmaf(hv, Wfc[k], o0);
    o1 = fmaf(hv, Wfc[33 + k], o1);
  }
  o0 = fmaf(mean, Wfc[32], o0);
  o1 = fmaf(mean, Wfc[65], o1);
  float m = fmaxf(o0, o1);
  float l = m + logf(expf(o0 - m) + expf(o1 - m));
  out[node * 2 + 0] = o0 - l;
  out[node * 2 + 1] = o1 - l;
}

extern "C" void kernel_launch(void* const* d_in, const int* in_sizes, int n_in,
                              void* d_out, int out_size, void* d_ws, size_t ws_size,
                              hipStream_t stream) {
  const float* x    = (const float*)d_in[0];
  const float* ew   = (const float*)d_in[1];
  const float* Wih1 = (const float*)d_in[2];
  const float* Whh1 = (const float*)d_in[3];
  const float* bih1 = (const float*)d_in[4];
  const float* bhh1 = (const float*)d_in[5];
  const float* ln_g = (const float*)d_in[6];
  const float* ln_b = (const float*)d_in[7];
  const float* Wih2 = (const float*)d_in[8];
  const float* Whh2 = (const float*)d_in[9];
  const float* bih2 = (const float*)d_in[10];
  const float* bhh2 = (const float*)d_in[11];
  const float* Wg1  = (const float*)d_in[12];
  const float* bg1  = (const float*)d_in[13];
  const float* Wg2  = (const float*)d_in[14];
  const float* bg2  = (const float*)d_in[15];
  const float* Wfc  = (const float*)d_in[16];
  const float* bfc  = (const float*)d_in[17];
  const int* ei     = (const int*)d_in[18];
  float* out = (float*)d_out;
  const int E = in_sizes[1];

  float* ws   = (float*)d_ws;
  float* h2   = ws;
  float* hW   = ws + 262144;
  float* agg  = ws + 524288;
  float* deg  = ws + 786432;
  float* dinv = ws + 794624;

  hipLaunchKernelGGL(deg_init, dim3(32), dim3(256), 0, stream, deg);
  hipLaunchKernelGGL(deg_acc, dim3((E + 255) / 256), dim3(256), 0, stream, ei, ew, deg, E);
  hipLaunchKernelGGL(lstm_fused, dim3(NNODES / 32), dim3(512), 0, stream,
                     x, Wih1, Whh1, bih1, bhh1, ln_g, ln_b,
                     Wih2, Whh2, bih2, bhh2, h2);
  hipLaunchKernelGGL(gcn_mm1, dim3(NNODES / 8), dim3(256), 0, stream, h2, Wg1, deg, dinv, hW, agg);
  hipLaunchKernelGGL(gcn_edge, dim3((E * 32 + 255) / 256), dim3(256), 0, stream, ei, ew, dinv, hW, agg, E);
  hipLaunchKernelGGL(gcn_mid, dim3(NNODES / 8), dim3(256), 0, stream, bg1, Wg2, dinv, hW, agg);
  hipLaunchKernelGGL(gcn_edge, dim3((E * 32 + 255) / 256), dim3(256), 0, stream, ei, ew, dinv, hW, agg, E);
  hipLaunchKernelGGL(final_k, dim3(NNODES / 256), dim3(256), 0, stream, h2, agg, bg2, Wfc, bfc, out);
}

// Round 7
// 498.223 us; speedup vs baseline: 1.1930x; 1.1930x over previous
//
#include <hip/hip_runtime.h>

typedef __attribute__((ext_vector_type(8))) short short8;
typedef __attribute__((ext_vector_type(4))) float float4v;

#define NNODES 8192
#define SEQLEN 256

static __device__ __forceinline__ float bf2f(unsigned short u) {
  union { unsigned u; float f; } v; v.u = ((unsigned)u) << 16; return v.f;
}
static __device__ __forceinline__ unsigned short f2bf(float f) {
  union { float f; unsigned u; } v; v.f = f;
  unsigned r = v.u + 0x7FFFu + ((v.u >> 16) & 1u);
  return (unsigned short)(r >> 16);
}
// z' pre-scaled by log2(e)
static __device__ __forceinline__ float sigmL(float zp) {
  float e = __builtin_amdgcn_exp2f(-zp);
  return __builtin_amdgcn_rcpf(1.f + e);
}
static __device__ __forceinline__ float tanhL(float zp) {
  float e = __builtin_amdgcn_exp2f(zp + zp);
  return (e - 1.f) * __builtin_amdgcn_rcpf(e + 1.f);
}
static __device__ __forceinline__ float tanhR(float x) {
  float e = __builtin_amdgcn_exp2f(2.88539008178f * fminf(x, 20.f));
  return (e - 1.f) * __builtin_amdgcn_rcpf(e + 1.f);
}
static __device__ __forceinline__ void split8(const float* v, short8& hi, short8& lo) {
#pragma unroll
  for (int j = 0; j < 8; ++j) {
    unsigned short h = f2bf(v[j]);
    hi[j] = (short)h;
    lo[j] = (short)f2bf(v[j] - bf2f(h));
  }
}

// v7: v5 structure (1 tile/wave, 8 waves/block, 512 blocks = 4 waves/SIMD)
// + v6 diet (log2-scaled gates, bias in MFMA C, LDS mu exchange)
// + x staged as float4 per 4 timesteps.
__global__ __launch_bounds__(512, 4)
void lstm_fused(const float* __restrict__ x,
                const float* __restrict__ Wih1, const float* __restrict__ Whh1,
                const float* __restrict__ bih1, const float* __restrict__ bhh1,
                const float* __restrict__ ln_g, const float* __restrict__ ln_b,
                const float* __restrict__ Wih2, const float* __restrict__ Whh2,
                const float* __restrict__ bih2, const float* __restrict__ bhh2,
                float* __restrict__ h2out)
{
  const int tid = threadIdx.x;
  const int w = tid >> 6;
  const int lane = tid & 63;
  const int c = lane & 15;
  const int q = lane >> 4;
  const int cn = lane >> 2;        // cell node 0..15
  const int ch = lane & 3;
  const int hid = w * 4 + ch;
  const int nodeBase = blockIdx.x * 16;
  const float L = 1.44269504089f;

  __shared__ __align__(16) float xlds[16 * 260];
  __shared__ __align__(16) float zbuf[16 * 132];
  __shared__ __align__(16) unsigned short h1p[16 * 40];
  __shared__ __align__(16) unsigned short h2p[16 * 40];
  __shared__ __align__(16) float mu2[32];

  for (int i = tid; i < 16 * 256; i += 512) {
    int nn = i >> 8, tt = i & 255;
    xlds[nn * 260 + tt] = x[(size_t)(nodeBase + nn) * SEQLEN + tt];
  }

  // ---- B fragments (col c -> brow), hi+lo split, scaled by L ----
  const int brow = (c & 3) * 32 + w * 4 + (c >> 2);
  short8 Bh1h, Bh1l, Bi2h, Bi2l, Bh2h, Bh2l;
  float Gpre, b1pre, b2pre;
  {
    float v[8];
#pragma unroll
    for (int j = 0; j < 8; ++j) v[j] = L * Whh1[brow * 32 + q * 8 + j];
    split8(v, Bh1h, Bh1l);
#pragma unroll
    for (int j = 0; j < 8; ++j) v[j] = L * Wih2[brow * 32 + q * 8 + j] * ln_g[q * 8 + j];
    split8(v, Bi2h, Bi2l);
#pragma unroll
    for (int j = 0; j < 8; ++j) v[j] = L * Whh2[brow * 32 + q * 8 + j];
    split8(v, Bh2h, Bh2l);
    float sG = 0.f, sB = 0.f;
    for (int k = 0; k < 32; ++k) {
      sG += Wih2[brow * 32 + k] * ln_g[k];
      sB += Wih2[brow * 32 + k] * ln_b[k];
    }
    Gpre = L * sG;
    b1pre = L * (bih1[brow] + bhh1[brow]);
    b2pre = L * (sB + bih2[brow] + bhh2[brow]);
  }
  const float4v C1 = {b1pre, b1pre, b1pre, b1pre};
  const float4v C2 = {b2pre, b2pre, b2pre, b2pre};
  const float4v z4 = {0.f, 0.f, 0.f, 0.f};
  float w1v[4];
#pragma unroll
  for (int g = 0; g < 4; ++g) w1v[g] = L * Wih1[g * 32 + hid];

  // loop-invariant LDS addresses
  int zW[4];
#pragma unroll
  for (int r = 0; r < 4; ++r) zW[r] = (q * 4 + r) * 132 + w * 16 + c;
  const int zR = cn * 132 + hid * 4;
  const int hWr = cn * 40 + hid;
  const int hRd = c * 40 + q * 8;

  short8 h1A = {0,0,0,0,0,0,0,0};
  short8 h2A = {0,0,0,0,0,0,0,0};
  float c1 = 0.f, c2 = 0.f, hv2 = 0.f;
  __syncthreads();

  for (int t4 = 0; t4 < SEQLEN / 4; ++t4) {
    float4v xq = *(const float4v*)&xlds[cn * 260 + t4 * 4];
#pragma unroll
    for (int tt = 0; tt < 4; ++tt) {
      // ---- layer1: z1 = h1 @ Whh1^T (+bias in C) ----
      float4v za = __builtin_amdgcn_mfma_f32_16x16x32_bf16(h1A, Bh1l, C1, 0, 0, 0);
      za = __builtin_amdgcn_mfma_f32_16x16x32_bf16(h1A, Bh1h, za, 0, 0, 0);
#pragma unroll
      for (int r = 0; r < 4; ++r) zbuf[zW[r]] = za[r];
      float4v zv = *(const float4v*)&zbuf[zR];   // intra-wave, lgkm-ordered

      // ---- cell layer1 ----
      {
        float xv = xq[tt];
        float zi = fmaf(xv, w1v[0], zv[0]);
        float zf = fmaf(xv, w1v[1], zv[1]);
        float zg = fmaf(xv, w1v[2], zv[2]);
        float zo = fmaf(xv, w1v[3], zv[3]);
        c1 = sigmL(zf) * c1 + sigmL(zi) * tanhL(zg);
        float hv = sigmL(zo) * tanhR(c1);
        h1p[hWr] = f2bf(hv);
      }
      __syncthreads();                           // B1
      h1A = *(const short8*)&h1p[hRd];

      // ---- LN stats (redundant per wave; lane holds node c) ----
      float s = 0.f, s2 = 0.f;
#pragma unroll
      for (int j = 0; j < 8; ++j) {
        float hf = bf2f((unsigned short)h1A[j]);
        s += hf; s2 = fmaf(hf, hf, s2);
      }
      s  += __shfl_xor(s, 16, 64);  s  += __shfl_xor(s, 32, 64);
      s2 += __shfl_xor(s2, 16, 64); s2 += __shfl_xor(s2, 32, 64);
      float mu = s * (1.f / 32.f);
      float var = s2 * (1.f / 32.f) - mu * mu;
      float rstd = rsqrtf(var + 1e-5f);
      if (q < 2) mu2[c * 2 + q] = (q == 0) ? rstd : rstd * mu;

      // ---- layer2 matmuls + folded-LN combine ----
      float4v da = __builtin_amdgcn_mfma_f32_16x16x32_bf16(h1A, Bi2l, z4, 0, 0, 0);
      da = __builtin_amdgcn_mfma_f32_16x16x32_bf16(h1A, Bi2h, da, 0, 0, 0);
      float4v db = __builtin_amdgcn_mfma_f32_16x16x32_bf16(h2A, Bh2l, C2, 0, 0, 0);
      db = __builtin_amdgcn_mfma_f32_16x16x32_bf16(h2A, Bh2h, db, 0, 0, 0);
#pragma unroll
      for (int r = 0; r < 4; ++r) {
        float2 ab = *(const float2*)&mu2[(q * 4 + r) * 2];  // own-wave write, lgkm-ordered
        zbuf[zW[r]] = fmaf(ab.x, da[r], fmaf(-ab.y, Gpre, db[r]));
      }
      float4v z2v = *(const float4v*)&zbuf[zR];

      // ---- cell layer2 ----
      c2 = sigmL(z2v[1]) * c2 + sigmL(z2v[0]) * tanhL(z2v[2]);
      hv2 = sigmL(z2v[3]) * tanhR(c2);
      h2p[hWr] = f2bf(hv2);
      __syncthreads();                           // B2
      h2A = *(const short8*)&h2p[hRd];
    }
  }
  h2out[(size_t)(nodeBase + cn) * 32 + hid] = hv2;
}

// ---------------- GCN (all f32) ----------------
__global__ void deg_init(float* __restrict__ deg) {
  int i = blockIdx.x * 256 + threadIdx.x;
  if (i < NNODES) deg[i] = 1.f;
}
__global__ void deg_acc(const int* __restrict__ ei, const float* __restrict__ ew,
                        float* __restrict__ deg, int E) {
  int e = blockIdx.x * 256 + threadIdx.x;
  if (e < E) atomicAdd(&deg[ei[E + e]], ew[e]);
}
__global__ void gcn_mm1(const float* __restrict__ h2, const float* __restrict__ Wg1,
                        const float* __restrict__ deg, float* __restrict__ dinv,
                        float* __restrict__ hW, float* __restrict__ agg) {
  __shared__ float wg[32 * 33];
  int tid = threadIdx.x;
  for (int i = tid; i < 1024; i += 256) wg[(i >> 5) * 33 + (i & 31)] = Wg1[i];
  __syncthreads();
  int nl = tid >> 5, j = tid & 31;
  int node = blockIdx.x * 8 + nl;
  const float* hr = h2 + (size_t)node * 32;
  float acc = 0.f;
#pragma unroll
  for (int k = 0; k < 32; ++k) acc = fmaf(hr[k], wg[k * 33 + j], acc);
  float dv = rsqrtf(deg[node]);
  if (j == 0) dinv[node] = dv;
  hW[(size_t)node * 32 + j] = acc;
  agg[(size_t)node * 32 + j] = acc * dv * dv;
}
__global__ void gcn_edge(const int* __restrict__ ei, const float* __restrict__ ew,
                         const float* __restrict__ dinv, const float* __restrict__ hW,
                         float* __restrict__ agg, int E) {
  int gid = blockIdx.x * 256 + threadIdx.x;
  int e = gid >> 5, j = gid & 31;
  if (e >= E) return;
  int s = ei[e], d = ei[E + e];
  float coeff = dinv[s] * ew[e] * dinv[d];
  atomicAdd(&agg[(size_t)d * 32 + j], coeff * hW[(size_t)s * 32 + j]);
}
__global__ void gcn_mid(const float* __restrict__ bg1, const float* __restrict__ Wg2,
                        const float* __restrict__ dinv,
                        float* __restrict__ hW, float* __restrict__ agg) {
  __shared__ float wg[32 * 33];
  __shared__ float g1buf[8][33];
  int tid = threadIdx.x;
  for (int i = tid; i < 1024; i += 256) wg[(i >> 5) * 33 + (i & 31)] = Wg2[i];
  int nl = tid >> 5, j = tid & 31;
  int node = blockIdx.x * 8 + nl;
  float v = agg[(size_t)node * 32 + j] + bg1[j];
  g1buf[nl][j] = (v > 0.f) ? v : expm1f(v);
  __syncthreads();
  float acc = 0.f;
#pragma unroll
  for (int k = 0; k < 32; ++k) acc = fmaf(g1buf[nl][k], wg[k * 33 + j], acc);
  float dv = dinv[node];
  hW[(size_t)node * 32 + j] = acc;
  agg[(size_t)node * 32 + j] = acc * dv * dv;
}
__global__ void final_k(const float* __restrict__ h2, const float* __restrict__ agg,
                        const float* __restrict__ bg2, const float* __restrict__ Wfc,
                        const float* __restrict__ bfc, float* __restrict__ out) {
  int node = blockIdx.x * 256 + threadIdx.x;
  if (node >= NNODES) return;
  const float* ar = agg + (size_t)node * 32;
  float msum = 0.f;
#pragma unroll
  for (int k = 0; k < 32; ++k) {
    float v = ar[k] + bg2[k];
    msum += (v > 0.f) ? v : expm1f(v);
  }
  float mean = msum * (1.f / 32.f);
  const float* hr = h2 + (size_t)node * 32;
  float o0 = bfc[0], o1 = bfc[1];
#pragma unroll
  for (int k = 0; k < 32; ++k) {
    float hv = hr[k];
    o0 = fmaf(hv, Wfc[k], o0);
    o1 = fmaf(hv, Wfc[33 + k], o1);
  }
  o0 = fmaf(mean, Wfc[32], o0);
  o1 = fmaf(mean, Wfc[65], o1);
  float m = fmaxf(o0, o1);
  float l = m + logf(expf(o0 - m) + expf(o1 - m));
  out[node * 2 + 0] = o0 - l;
  out[node * 2 + 1] = o1 - l;
}

extern "C" void kernel_launch(void* const* d_in, const int* in_sizes, int n_in,
                              void* d_out, int out_size, void* d_ws, size_t ws_size,
                              hipStream_t stream) {
  const float* x    = (const float*)d_in[0];
  const float* ew   = (const float*)d_in[1];
  const float* Wih1 = (const float*)d_in[2];
  const float* Whh1 = (const float*)d_in[3];
  const float* bih1 = (const float*)d_in[4];
  const float* bhh1 = (const float*)d_in[5];
  const float* ln_g = (const float*)d_in[6];
  const float* ln_b = (const float*)d_in[7];
  const float* Wih2 = (const float*)d_in[8];
  const float* Whh2 = (const float*)d_in[9];
  const float* bih2 = (const float*)d_in[10];
  const float* bhh2 = (const float*)d_in[11];
  const float* Wg1  = (const float*)d_in[12];
  const float* bg1  = (const float*)d_in[13];
  const float* Wg2  = (const float*)d_in[14];
  const float* bg2  = (const float*)d_in[15];
  const float* Wfc  = (const float*)d_in[16];
  const float* bfc  = (const float*)d_in[17];
  const int* ei     = (const int*)d_in[18];
  float* out = (float*)d_out;
  const int E = in_sizes[1];

  float* ws   = (float*)d_ws;
  float* h2   = ws;
  float* hW   = ws + 262144;
  float* agg  = ws + 524288;
  float* deg  = ws + 786432;
  float* dinv = ws + 794624;

  hipLaunchKernelGGL(deg_init, dim3(32), dim3(256), 0, stream, deg);
  hipLaunchKernelGGL(deg_acc, dim3((E + 255) / 256), dim3(256), 0, stream, ei, ew, deg, E);
  hipLaunchKernelGGL(lstm_fused, dim3(NNODES / 16), dim3(512), 0, stream,
                     x, Wih1, Whh1, bih1, bhh1, ln_g, ln_b,
                     Wih2, Whh2, bih2, bhh2, h2);
  hipLaunchKernelGGL(gcn_mm1, dim3(NNODES / 8), dim3(256), 0, stream, h2, Wg1, deg, dinv, hW, agg);
  hipLaunchKernelGGL(gcn_edge, dim3((E * 32 + 255) / 256), dim3(256), 0, stream, ei, ew, dinv, hW, agg, E);
  hipLaunchKernelGGL(gcn_mid, dim3(NNODES / 8), dim3(256), 0, stream, bg1, Wg2, dinv, hW, agg);
  hipLaunchKernelGGL(gcn_edge, dim3((E * 32 + 255) / 256), dim3(256), 0, stream, ei, ew, dinv, hW, agg, E);
  hipLaunchKernelGGL(final_k, dim3(NNODES / 256), dim3(256), 0, stream, h2, agg, bg2, Wfc, bfc, out);
}